// Round 17
// baseline (99.157 us; speedup 1.0000x reference)
//
#include <hip/hip_runtime.h>
#include <cfloat>

#define KC    32768
#define NPTS  8192
#define NC    256
#define CHUNK (KC / NC)                // 128

__device__ __forceinline__ float min3f(float a, float b, float c) {
    float d; asm("v_min3_f32 %0, %1, %2, %3" : "=v"(d) : "v"(a), "v"(b), "v"(c)); return d;
}

// ---------------- K0: pack E into SoA (E0|E1|E2|E3|B) for uniform scalar loads
__global__ __launch_bounds__(256) void k_prep(const float* __restrict__ E,
                                              float* __restrict__ ec) {
#pragma clang fp contract(off)
    const int k = blockIdx.x * 256 + threadIdx.x;
    float4 e = ((const float4*)E)[k];
    ec[k]          = e.x;
    ec[KC + k]     = e.y;
    ec[2 * KC + k] = e.z;
    ec[3 * KC + k] = e.w;
    // bnorm: squares individually rounded, sequential adds (R1-verified)
    ec[4 * KC + k] = ((e.x * e.x + e.y * e.y) + e.z * e.z) + e.w * e.w;
}

// ---------------- K1: per-chunk MIN-DISTANCE ONLY. lane = point; code data is
// wave-uniform -> SGPRs; SCALAR full-rate VALU (pk_f32 measured half-rate).
// Chain: xm = -2x prescaled, mm = fma-chain = -2m EXACT (pow2 scaling commutes
// with rounding, R16-verified); d = fl(fl(a+b) + mm) == reference bitwise.
__global__ __launch_bounds__(256) void k_dist(const float* __restrict__ x,
                                              const float* __restrict__ ec,
                                              float* __restrict__ dmn) {
#pragma clang fp contract(off)
    const float* E0 = ec;
    const float* E1 = ec + KC;
    const float* E2 = ec + 2 * KC;
    const float* E3 = ec + 3 * KC;
    const float* Bb = ec + 4 * KC;

    const int chunk = blockIdx.x;
    const int tid   = threadIdx.x;
    const int p     = blockIdx.y * 256 + tid;  // 32 y-blocks x 256 threads
    const int kb    = chunk * CHUNK;           // uniform

    const int t  = p >> 12, s = p & 4095;
    const int xb = t * 16384 + s;
    const float x0 = x[xb];
    const float x1 = x[xb + 4096];
    const float x2 = x[xb + 8192];
    const float x3 = x[xb + 12288];
    const float a  = ((x0 * x0 + x1 * x1) + x2 * x2) + x3 * x3;
    const float xm0 = -2.0f * x0, xm1 = -2.0f * x1;
    const float xm2 = -2.0f * x2, xm3 = -2.0f * x3;

    float bd = FLT_MAX;
#pragma unroll 4
    for (int q = 0; q < CHUNK; q += 2) {
        // all E*/Bb indices are wave-uniform -> s_load + SGPR operands
        const float e00 = E0[kb + q],     e01 = E0[kb + q + 1];
        const float e10 = E1[kb + q],     e11 = E1[kb + q + 1];
        const float e20 = E2[kb + q],     e21 = E2[kb + q + 1];
        const float e30 = E3[kb + q],     e31 = E3[kb + q + 1];
        const float b0  = Bb[kb + q],     b1  = Bb[kb + q + 1];

        // mm = -2m exactly (prescaled chain, same rounding sequence as ref)
        float mm0 = __builtin_fmaf(xm3, e30, __builtin_fmaf(xm2, e20,
                     __builtin_fmaf(xm1, e10, xm0 * e00)));
        float d0  = (a + b0) + mm0;            // fl(fl(a+b) - 2m)
        float mm1 = __builtin_fmaf(xm3, e31, __builtin_fmaf(xm2, e21,
                     __builtin_fmaf(xm1, e11, xm0 * e01)));
        float d1  = (a + b1) + mm1;
        bd = min3f(bd, d0, d1);                // min only (index via rescan)
    }
    dmn[chunk * NPTS + p] = bd;
}

// ---------------- K2: merge chunk-mins, recover first-index k, gather, loss
// (verified absmax 0.0 in R12/R14/R16 at NC=256)
__global__ __launch_bounds__(256) void k_merge(const float* __restrict__ x,
                                               const float* __restrict__ E,
                                               const float* __restrict__ dmn,
                                               float* __restrict__ out,
                                               double* __restrict__ partials) {
#pragma clang fp contract(off)
    const int tid  = threadIdx.x;
    const int sub  = tid & 7;
    const int pidx = tid >> 3;                 // 0..31
    const int p    = blockIdx.x * 32 + pidx;   // 256 blocks x 32 points
    const int t    = p >> 12, s = p & 4095;
    const int xb   = t * 16384 + s;

    const float x0 = x[xb];
    const float x1 = x[xb + 4096];
    const float x2 = x[xb + 8192];
    const float x3 = x[xb + 12288];
    const float a  = ((x0 * x0 + x1 * x1) + x2 * x2) + x3 * x3;

    // min over chunks, tie -> smaller chunk id (lexicographic)
    float bd = FLT_MAX;
    int   bc = 0x7fffffff;
#pragma unroll 8
    for (int i = 0; i < NC / 8; ++i) {
        const int c = sub + 8 * i;             // ascending per sub
        float d = dmn[c * NPTS + p];
        if (d < bd) { bd = d; bc = c; }        // strict <: earliest c in sub set
    }
#pragma unroll
    for (int m = 1; m <= 4; m <<= 1) {
        float d2 = __shfl_xor(bd, m);
        int   c2 = __shfl_xor(bc, m);
        if (d2 < bd || (d2 == bd && c2 < bc)) { bd = d2; bc = c2; }
    }

    // rescan chunk bc: sub handles CHUNK/8 = 16 consecutive codes
    const int kb = bc * CHUNK;
    int jloc = 1 << 30;
    for (int jj = 0; jj < CHUNK / 8; ++jj) {
        const int j = sub * (CHUNK / 8) + jj;
        float4 e = ((const float4*)E)[kb + j];
        float bn = ((e.x * e.x + e.y * e.y) + e.z * e.z) + e.w * e.w;
        float m_ = __builtin_fmaf(x3, e.w, __builtin_fmaf(x2, e.z,
                    __builtin_fmaf(x1, e.y, x0 * e.x)));
        float t_ = a + bn;
        float d_ = __builtin_fmaf(-2.0f, m_, t_);  // == k_dist's d bitwise
        if (d_ == bd) jloc = min(jloc, j);     // ascending j -> first match
    }
#pragma unroll
    for (int m = 1; m <= 4; m <<= 1) jloc = min(jloc, __shfl_xor(jloc, m));
    const int bk = kb + (jloc & (CHUNK - 1));  // clamp guards OOB if mismatch

    double ls = 0.0;
    if (sub < 4) {                             // one channel per sub-lane
        const int ch  = sub;
        const int idx = xb + ch * 4096;
        float xv   = x[idx];
        float ev   = E[bk * 4 + ch];
        float diff = ev - xv;                  // fl(z_q - x)
        float sq   = diff * diff;              // fl(diff^2)
        out[idx]   = xv + diff;                // z_q_st = fl(x + fl(z_q - x))
        ls = (double)sq;
        if (ch == 0) out[32769 + p] = (float)bk;  // codes as float
    }
#pragma unroll
    for (int m = 1; m < 64; m <<= 1) ls += __shfl_xor(ls, m);
    __shared__ double sred[4];
    if ((tid & 63) == 0) sred[tid >> 6] = ls;
    __syncthreads();
    if (tid == 0) partials[blockIdx.x] = sred[0] + sred[1] + sred[2] + sred[3];
}

// ---------------- K3: finalize qloss
__global__ void k_loss(const double* __restrict__ partials,
                       float* __restrict__ out) {
#pragma clang fp contract(off)
    if (threadIdx.x == 0 && blockIdx.x == 0) {
        double sum = 0.0;
        for (int i = 0; i < 256; ++i) sum += partials[i];
        float mu = (float)(sum * (1.0 / 32768.0));   // /32768 exact
        float q  = mu + 0.1f * mu;                   // mean1 + BETA*mean2
        out[32768] = q;
    }
}

extern "C" void kernel_launch(void* const* d_in, const int* in_sizes, int n_in,
                              void* d_out, int out_size, void* d_ws, size_t ws_size,
                              hipStream_t stream) {
    const float* x = (const float*)d_in[0];   // (1,2,4,64,64)
    const float* E = (const float*)d_in[1];   // (32768,4)
    float* out = (float*)d_out;               // 40961 floats

    char* ws = (char*)d_ws;
    double* partials = (double*)ws;                    // 2 KB
    float*  ec       = (float*)(ws + 2048);            // 5*KC*4 = 640 KB SoA
    float*  dmn      = (float*)(ws + 2048 + 5 * KC * 4); // 8.4 MB (proven)

    k_prep<<<KC / 256, 256, 0, stream>>>(E, ec);
    dim3 g(NC, NPTS / 256);                    // 256 x 32 = 8192 blocks
    k_dist<<<g, 256, 0, stream>>>(x, ec, dmn);
    k_merge<<<NPTS / 32, 256, 0, stream>>>(x, E, dmn, out, partials);
    k_loss<<<1, 64, 0, stream>>>(partials, out);
}

// Round 18
// 55.964 us; speedup vs baseline: 1.7718x; 1.7718x over previous
//
#include <hip/hip_runtime.h>
#include <cfloat>

#define KC    32768
#define NPTS  8192
#define TPB   256
#define PPT   8
#define PTS_PER_BLK (TPB * PPT)        // 2048
#define NPB   (NPTS / PTS_PER_BLK)     // 4
#define NC    512
#define CHUNK (KC / NC)                // 64

__device__ __forceinline__ float min3f(float a, float b, float c) {
    float d; asm("v_min3_f32 %0, %1, %2, %3" : "=v"(d) : "v"(a), "v"(b), "v"(c)); return d;
}

// ---------------- K1: per-chunk MIN-DISTANCE ONLY, 8 points/thread.
// R12's proven LDS-broadcast delivery + SCALAR full-rate VALU (pk_f32 is
// half-rate: R12/R14/R16 all pinned at its 43 µs floor; scalar floor = 22 µs).
// Chain: xm = -2x prescaled; mm = fma(xm3,e3,fma(xm2,e2,fma(xm1,e1,xm0*e0)))
// = -2m EXACT (pow2 scale commutes with rounding); d = (a+b) + mm — bitwise
// equal to reference fl(fl(a+b)-fl(2m)). Verified absmax 0 in R16/R17.
__global__ __launch_bounds__(TPB) void k_dist(const float* __restrict__ x,
                                              const float* __restrict__ E,
                                              float* __restrict__ dmn) {
#pragma clang fp contract(off)
    __shared__ __align__(16) float lds[5 * CHUNK];
    float* exL = lds;
    float* eyL = lds + CHUNK;
    float* ezL = lds + 2 * CHUNK;
    float* ewL = lds + 3 * CHUNK;
    float* bL  = lds + 4 * CHUNK;

    const int chunk = blockIdx.x;
    const int pblk  = blockIdx.y;
    const int tid   = threadIdx.x;
    const int kbase = chunk * CHUNK;

    // Stage SoA + fused bnorm (squares individually rounded, sequential adds)
    for (int i = tid; i < CHUNK; i += TPB) {
        float4 e = ((const float4*)E)[kbase + i];
        exL[i] = e.x; eyL[i] = e.y; ezL[i] = e.z; ewL[i] = e.w;
        bL[i]  = ((e.x * e.x + e.y * e.y) + e.z * e.z) + e.w * e.w;
    }
    __syncthreads();

    // 8 points/thread: prescaled xm0-3 + unscaled a  (5 VGPR/point)
    float xm0[PPT], xm1[PPT], xm2[PPT], xm3[PPT], av[PPT];
#pragma unroll
    for (int i = 0; i < PPT; ++i) {
        const int p  = pblk * PTS_PER_BLK + i * TPB + tid;
        const int t  = p >> 12, s = p & 4095;
        const int xb = t * 16384 + s;
        const float x0 = x[xb];
        const float x1 = x[xb + 4096];
        const float x2 = x[xb + 8192];
        const float x3 = x[xb + 12288];
        av[i]  = ((x0 * x0 + x1 * x1) + x2 * x2) + x3 * x3;
        xm0[i] = -2.0f * x0; xm1[i] = -2.0f * x1;
        xm2[i] = -2.0f * x2; xm3[i] = -2.0f * x3;
    }

    float bd[PPT];
#pragma unroll
    for (int i = 0; i < PPT; ++i) bd[i] = FLT_MAX;

#pragma unroll 2
    for (int q = 0; q < CHUNK / 4; ++q) {      // 4 codes x 8 points per iter
        float4 vx = *(const float4*)(exL + 4 * q);
        float4 vy = *(const float4*)(eyL + 4 * q);
        float4 vz = *(const float4*)(ezL + 4 * q);
        float4 vw = *(const float4*)(ewL + 4 * q);
        float4 vb = *(const float4*)(bL  + 4 * q);

#pragma unroll
        for (int i = 0; i < PPT; ++i) {
            // four codes, scalar full-rate chain each
            float mmA = __builtin_fmaf(xm3[i], vw.x, __builtin_fmaf(xm2[i], vz.x,
                         __builtin_fmaf(xm1[i], vy.x, xm0[i] * vx.x)));
            float dA  = (av[i] + vb.x) + mmA;
            float mmB = __builtin_fmaf(xm3[i], vw.y, __builtin_fmaf(xm2[i], vz.y,
                         __builtin_fmaf(xm1[i], vy.y, xm0[i] * vx.y)));
            float dB  = (av[i] + vb.y) + mmB;
            float mmC = __builtin_fmaf(xm3[i], vw.z, __builtin_fmaf(xm2[i], vz.z,
                         __builtin_fmaf(xm1[i], vy.z, xm0[i] * vx.z)));
            float dC  = (av[i] + vb.z) + mmC;
            float mmD = __builtin_fmaf(xm3[i], vw.w, __builtin_fmaf(xm2[i], vz.w,
                         __builtin_fmaf(xm1[i], vy.w, xm0[i] * vx.w)));
            float dD  = (av[i] + vb.w) + mmD;
            bd[i] = min3f(min3f(bd[i], dA, dB), dC, dD);   // min only
        }
    }
#pragma unroll
    for (int i = 0; i < PPT; ++i) {
        const int p = pblk * PTS_PER_BLK + i * TPB + tid;
        dmn[chunk * NPTS + p] = bd[i];
    }
}

// ---------------- K2: merge chunk-mins, recover first-index k, gather, loss
// (NC=512 path verified absmax 0.0 in R14; chain verified R16/R17)
__global__ __launch_bounds__(256) void k_merge(const float* __restrict__ x,
                                               const float* __restrict__ E,
                                               const float* __restrict__ dmn,
                                               float* __restrict__ out,
                                               double* __restrict__ partials) {
#pragma clang fp contract(off)
    const int tid  = threadIdx.x;
    const int sub  = tid & 7;
    const int pidx = tid >> 3;                 // 0..31
    const int p    = blockIdx.x * 32 + pidx;   // 256 blocks x 32 points
    const int t    = p >> 12, s = p & 4095;
    const int xb   = t * 16384 + s;

    const float x0 = x[xb];
    const float x1 = x[xb + 4096];
    const float x2 = x[xb + 8192];
    const float x3 = x[xb + 12288];
    const float a  = ((x0 * x0 + x1 * x1) + x2 * x2) + x3 * x3;

    // min over chunks, tie -> smaller chunk id (lexicographic)
    float bd = FLT_MAX;
    int   bc = 0x7fffffff;
#pragma unroll 8
    for (int i = 0; i < NC / 8; ++i) {
        const int c = sub + 8 * i;             // ascending per sub
        float d = dmn[c * NPTS + p];
        if (d < bd) { bd = d; bc = c; }        // strict <: earliest c in sub set
    }
#pragma unroll
    for (int m = 1; m <= 4; m <<= 1) {
        float d2 = __shfl_xor(bd, m);
        int   c2 = __shfl_xor(bc, m);
        if (d2 < bd || (d2 == bd && c2 < bc)) { bd = d2; bc = c2; }
    }

    // rescan chunk bc: sub handles CHUNK/8 = 8 consecutive codes
    const int kb = bc * CHUNK;
    int jloc = 1 << 30;
    for (int jj = 0; jj < CHUNK / 8; ++jj) {
        const int j = sub * (CHUNK / 8) + jj;
        float4 e = ((const float4*)E)[kb + j];
        float bn = ((e.x * e.x + e.y * e.y) + e.z * e.z) + e.w * e.w;
        float m_ = __builtin_fmaf(x3, e.w, __builtin_fmaf(x2, e.z,
                    __builtin_fmaf(x1, e.y, x0 * e.x)));
        float t_ = a + bn;
        float d_ = __builtin_fmaf(-2.0f, m_, t_);  // == k_dist's d bitwise
        if (d_ == bd) jloc = min(jloc, j);     // ascending j -> first match
    }
#pragma unroll
    for (int m = 1; m <= 4; m <<= 1) jloc = min(jloc, __shfl_xor(jloc, m));
    const int bk = kb + (jloc & (CHUNK - 1));  // clamp guards OOB if mismatch

    double ls = 0.0;
    if (sub < 4) {                             // one channel per sub-lane
        const int ch  = sub;
        const int idx = xb + ch * 4096;
        float xv   = x[idx];
        float ev   = E[bk * 4 + ch];
        float diff = ev - xv;                  // fl(z_q - x)
        float sq   = diff * diff;              // fl(diff^2)
        out[idx]   = xv + diff;                // z_q_st = fl(x + fl(z_q - x))
        ls = (double)sq;
        if (ch == 0) out[32769 + p] = (float)bk;  // codes as float
    }
#pragma unroll
    for (int m = 1; m < 64; m <<= 1) ls += __shfl_xor(ls, m);
    __shared__ double sred[4];
    if ((tid & 63) == 0) sred[tid >> 6] = ls;
    __syncthreads();
    if (tid == 0) partials[blockIdx.x] = sred[0] + sred[1] + sred[2] + sred[3];
}

// ---------------- K3: finalize qloss
__global__ void k_loss(const double* __restrict__ partials,
                       float* __restrict__ out) {
#pragma clang fp contract(off)
    if (threadIdx.x == 0 && blockIdx.x == 0) {
        double sum = 0.0;
        for (int i = 0; i < 256; ++i) sum += partials[i];
        float mu = (float)(sum * (1.0 / 32768.0));   // /32768 exact
        float q  = mu + 0.1f * mu;                   // mean1 + BETA*mean2
        out[32768] = q;
    }
}

extern "C" void kernel_launch(void* const* d_in, const int* in_sizes, int n_in,
                              void* d_out, int out_size, void* d_ws, size_t ws_size,
                              hipStream_t stream) {
    const float* x = (const float*)d_in[0];   // (1,2,4,64,64)
    const float* E = (const float*)d_in[1];   // (32768,4)
    float* out = (float*)d_out;               // 40961 floats

    char* ws = (char*)d_ws;
    double* partials = (double*)ws;                    // 2 KB
    float*  dmn      = (float*)(ws + 2048);            // 512*8192*4 = 16 MB (proven R14)

    dim3 g(NC, NPB);                           // 512 x 4 = 2048 blocks
    k_dist<<<g, TPB, 0, stream>>>(x, E, dmn);
    k_merge<<<NPTS / 32, 256, 0, stream>>>(x, E, dmn, out, partials);
    k_loss<<<1, 64, 0, stream>>>(partials, out);
}

// Round 19
// 50.420 us; speedup vs baseline: 1.9666x; 1.1100x over previous
//
#include <hip/hip_runtime.h>
#include <cfloat>

#define KC    32768
#define NPTS  8192
#define TPB   256
#define PPT   8
#define PTS_PER_BLK (TPB * PPT)        // 2048
#define NPB   (NPTS / PTS_PER_BLK)     // 4
#define NC    256
#define CHUNK (KC / NC)                // 128

__device__ __forceinline__ float min3f(float a, float b, float c) {
    float d; asm("v_min3_f32 %0, %1, %2, %3" : "=v"(d) : "v"(a), "v"(b), "v"(c)); return d;
}

// ---------------- K1: per-chunk MIN-DISTANCE ONLY, 8 points/thread.
// Scalar full-rate VALU + LDS broadcast (R18 body, at the measured ~44 µs
// VALU instruction-throughput wall). Chain: xm = -2x prescaled; mm = -2m
// EXACT; d = (a+b) + mm == reference fl(fl(a+b)-fl(2m)) bitwise (R16/R17/R18).
__global__ __launch_bounds__(TPB) void k_dist(const float* __restrict__ x,
                                              const float* __restrict__ E,
                                              float* __restrict__ dmn) {
#pragma clang fp contract(off)
    __shared__ __align__(16) float lds[5 * CHUNK];
    float* exL = lds;
    float* eyL = lds + CHUNK;
    float* ezL = lds + 2 * CHUNK;
    float* ewL = lds + 3 * CHUNK;
    float* bL  = lds + 4 * CHUNK;

    const int chunk = blockIdx.x;
    const int pblk  = blockIdx.y;
    const int tid   = threadIdx.x;
    const int kbase = chunk * CHUNK;

    // Stage SoA + fused bnorm (squares individually rounded, sequential adds)
    for (int i = tid; i < CHUNK; i += TPB) {
        float4 e = ((const float4*)E)[kbase + i];
        exL[i] = e.x; eyL[i] = e.y; ezL[i] = e.z; ewL[i] = e.w;
        bL[i]  = ((e.x * e.x + e.y * e.y) + e.z * e.z) + e.w * e.w;
    }
    __syncthreads();

    // 8 points/thread: prescaled xm0-3 + unscaled a  (5 VGPR/point)
    float xm0[PPT], xm1[PPT], xm2[PPT], xm3[PPT], av[PPT];
#pragma unroll
    for (int i = 0; i < PPT; ++i) {
        const int p  = pblk * PTS_PER_BLK + i * TPB + tid;
        const int t  = p >> 12, s = p & 4095;
        const int xb = t * 16384 + s;
        const float x0 = x[xb];
        const float x1 = x[xb + 4096];
        const float x2 = x[xb + 8192];
        const float x3 = x[xb + 12288];
        av[i]  = ((x0 * x0 + x1 * x1) + x2 * x2) + x3 * x3;
        xm0[i] = -2.0f * x0; xm1[i] = -2.0f * x1;
        xm2[i] = -2.0f * x2; xm3[i] = -2.0f * x3;
    }

    float bd[PPT];
#pragma unroll
    for (int i = 0; i < PPT; ++i) bd[i] = FLT_MAX;

#pragma unroll 2
    for (int q = 0; q < CHUNK / 4; ++q) {      // 4 codes x 8 points per iter
        float4 vx = *(const float4*)(exL + 4 * q);
        float4 vy = *(const float4*)(eyL + 4 * q);
        float4 vz = *(const float4*)(ezL + 4 * q);
        float4 vw = *(const float4*)(ewL + 4 * q);
        float4 vb = *(const float4*)(bL  + 4 * q);

#pragma unroll
        for (int i = 0; i < PPT; ++i) {
            float mmA = __builtin_fmaf(xm3[i], vw.x, __builtin_fmaf(xm2[i], vz.x,
                         __builtin_fmaf(xm1[i], vy.x, xm0[i] * vx.x)));
            float dA  = (av[i] + vb.x) + mmA;
            float mmB = __builtin_fmaf(xm3[i], vw.y, __builtin_fmaf(xm2[i], vz.y,
                         __builtin_fmaf(xm1[i], vy.y, xm0[i] * vx.y)));
            float dB  = (av[i] + vb.y) + mmB;
            float mmC = __builtin_fmaf(xm3[i], vw.z, __builtin_fmaf(xm2[i], vz.z,
                         __builtin_fmaf(xm1[i], vy.z, xm0[i] * vx.z)));
            float dC  = (av[i] + vb.z) + mmC;
            float mmD = __builtin_fmaf(xm3[i], vw.w, __builtin_fmaf(xm2[i], vz.w,
                         __builtin_fmaf(xm1[i], vy.w, xm0[i] * vx.w)));
            float dD  = (av[i] + vb.w) + mmD;
            bd[i] = min3f(min3f(bd[i], dA, dB), dC, dD);   // min only
        }
    }
#pragma unroll
    for (int i = 0; i < PPT; ++i) {
        const int p = pblk * PTS_PER_BLK + i * TPB + tid;
        dmn[chunk * NPTS + p] = bd[i];
    }
}

// ---------------- K2: merge chunk-mins, recover first-index k, gather, loss
// (NC=256 path verified absmax 0.0 in R12/R16/R17)
__global__ __launch_bounds__(256) void k_merge(const float* __restrict__ x,
                                               const float* __restrict__ E,
                                               const float* __restrict__ dmn,
                                               float* __restrict__ out,
                                               double* __restrict__ partials) {
#pragma clang fp contract(off)
    const int tid  = threadIdx.x;
    const int sub  = tid & 7;
    const int pidx = tid >> 3;                 // 0..31
    const int p    = blockIdx.x * 32 + pidx;   // 256 blocks x 32 points
    const int t    = p >> 12, s = p & 4095;
    const int xb   = t * 16384 + s;

    const float x0 = x[xb];
    const float x1 = x[xb + 4096];
    const float x2 = x[xb + 8192];
    const float x3 = x[xb + 12288];
    const float a  = ((x0 * x0 + x1 * x1) + x2 * x2) + x3 * x3;

    // min over chunks, tie -> smaller chunk id (lexicographic)
    float bd = FLT_MAX;
    int   bc = 0x7fffffff;
#pragma unroll 8
    for (int i = 0; i < NC / 8; ++i) {
        const int c = sub + 8 * i;             // ascending per sub
        float d = dmn[c * NPTS + p];
        if (d < bd) { bd = d; bc = c; }        // strict <: earliest c in sub set
    }
#pragma unroll
    for (int m = 1; m <= 4; m <<= 1) {
        float d2 = __shfl_xor(bd, m);
        int   c2 = __shfl_xor(bc, m);
        if (d2 < bd || (d2 == bd && c2 < bc)) { bd = d2; bc = c2; }
    }

    // rescan chunk bc: sub handles CHUNK/8 = 16 consecutive codes
    const int kb = bc * CHUNK;
    int jloc = 1 << 30;
    for (int jj = 0; jj < CHUNK / 8; ++jj) {
        const int j = sub * (CHUNK / 8) + jj;
        float4 e = ((const float4*)E)[kb + j];
        float bn = ((e.x * e.x + e.y * e.y) + e.z * e.z) + e.w * e.w;
        float m_ = __builtin_fmaf(x3, e.w, __builtin_fmaf(x2, e.z,
                    __builtin_fmaf(x1, e.y, x0 * e.x)));
        float t_ = a + bn;
        float d_ = __builtin_fmaf(-2.0f, m_, t_);  // == k_dist's d bitwise
        if (d_ == bd) jloc = min(jloc, j);     // ascending j -> first match
    }
#pragma unroll
    for (int m = 1; m <= 4; m <<= 1) jloc = min(jloc, __shfl_xor(jloc, m));
    const int bk = kb + (jloc & (CHUNK - 1));  // clamp guards OOB if mismatch

    double ls = 0.0;
    if (sub < 4) {                             // one channel per sub-lane
        const int ch  = sub;
        const int idx = xb + ch * 4096;
        float xv   = x[idx];
        float ev   = E[bk * 4 + ch];
        float diff = ev - xv;                  // fl(z_q - x)
        float sq   = diff * diff;              // fl(diff^2)
        out[idx]   = xv + diff;                // z_q_st = fl(x + fl(z_q - x))
        ls = (double)sq;
        if (ch == 0) out[32769 + p] = (float)bk;  // codes as float
    }
#pragma unroll
    for (int m = 1; m < 64; m <<= 1) ls += __shfl_xor(ls, m);
    __shared__ double sred[4];
    if ((tid & 63) == 0) sred[tid >> 6] = ls;
    __syncthreads();
    if (tid == 0) partials[blockIdx.x] = sred[0] + sred[1] + sred[2] + sred[3];
}

// ---------------- K3: finalize qloss
__global__ void k_loss(const double* __restrict__ partials,
                       float* __restrict__ out) {
#pragma clang fp contract(off)
    if (threadIdx.x == 0 && blockIdx.x == 0) {
        double sum = 0.0;
        for (int i = 0; i < 256; ++i) sum += partials[i];
        float mu = (float)(sum * (1.0 / 32768.0));   // /32768 exact
        float q  = mu + 0.1f * mu;                   // mean1 + BETA*mean2
        out[32768] = q;
    }
}

extern "C" void kernel_launch(void* const* d_in, const int* in_sizes, int n_in,
                              void* d_out, int out_size, void* d_ws, size_t ws_size,
                              hipStream_t stream) {
    const float* x = (const float*)d_in[0];   // (1,2,4,64,64)
    const float* E = (const float*)d_in[1];   // (32768,4)
    float* out = (float*)d_out;               // 40961 floats

    char* ws = (char*)d_ws;
    double* partials = (double*)ws;                    // 2 KB
    float*  dmn      = (float*)(ws + 2048);            // 256*8192*4 = 8.4 MB (proven)

    dim3 g(NC, NPB);                           // 256 x 4 = 1024 blocks
    k_dist<<<g, TPB, 0, stream>>>(x, E, dmn);
    k_merge<<<NPTS / 32, 256, 0, stream>>>(x, E, dmn, out, partials);
    k_loss<<<1, 64, 0, stream>>>(partials, out);
}